// Round 15
// baseline (514.973 us; speedup 1.0000x reference)
//
#include <hip/hip_runtime.h>
#include <hip/hip_bf16.h>

typedef __attribute__((ext_vector_type(4))) float floatx4;
typedef __attribute__((ext_vector_type(16))) float floatx16;
typedef __attribute__((ext_vector_type(8))) __bf16 bf16x8;
typedef unsigned short ushort_t;

#define NENT  700
#define EMB   256
#define KDIM  1024
#define NDIM  512
#define HROWS 720   // 90*8: every row written by prep_kernel; reads stay <= 709
#define NPAIR 340000

// ws byte offsets — total ~7.4 MB (WS_ENT retained but unused since R22)
#define WS_HA   0
#define WS_HB   (WS_HA + HROWS*KDIM*2)
#define WS_W2H  (WS_HB + HROWS*KDIM*2)
#define WS_ENT  (WS_W2H + NDIM*KDIM*2)
#define WS_LG   (WS_ENT + NENT*EMB*4)

__device__ __forceinline__ float ldin(const void* p, int i, int isbf) {
    return isbf ? __bfloat162float(((const __hip_bfloat16*)p)[i])
                : ((const float*)p)[i];
}

// per-wave dtype sniff of entity_embedding; deterministic, no cross-kernel dep
__device__ __forceinline__ int detect_bf16(const ushort_t* __restrict__ w) {
    int t = threadIdx.x & 63;
    int e = (w[2*t] >> 7) & 0xFF;
    unsigned long long m = __ballot(e >= 100 && e <= 126);
    return (__popcll(m) >= 48) ? 1 : 0;   // bf16 ~64 hits, f32 ~7
}

// lgkmcnt(0) only; vmcnt untouched -> global prefetches survive the barrier
#define LDS_BARRIER() do { __builtin_amdgcn_s_waitcnt(0xC07F); __builtin_amdgcn_s_barrier(); } while (0)

// ---------------- stage 1 (R24 prep, heavy path unchanged) ----------------
// blocks 0..719: heavy. b&1=part, (b>>1)&3=nsplit, b>>3=row-tile (8 rows).
// blocks 720..975: W2H repack — R27: re-indexed for the 32x32x16 B layout.
//   frag(half, k16, g32): lane l holds n = half*256 + g32*32 + (l&31),
//                         k = k16*16 + (l>>5)*8 + j   (j = 0..7)
//   element offset = ((half*64 + k16)*8 + g32)*512 + lane*8 + j  == g*8 + j.
__global__ void prep_kernel(const void* __restrict__ E, const void* __restrict__ Went,
                            const void* __restrict__ W1, const void* __restrict__ b1,
                            const void* __restrict__ W2, __hip_bfloat16* __restrict__ W2H,
                            __hip_bfloat16* __restrict__ HA, __hip_bfloat16* __restrict__ HB,
                            void* __restrict__ out) {
    int isbf = detect_bf16((const ushort_t*)E);
    if (blockIdx.x < 720) {
        int part = blockIdx.x & 1;
        int ns   = (blockIdx.x >> 1) & 3;
        int rt   = blockIdx.x >> 3;          // 0..89
        int ib   = rt * 8;
        int t    = threadIdx.x;
        __shared__ float eL[8][EMB];      // E rows (f32)
        __shared__ float rows[8][EMB];    // ent rows (f32)
#pragma unroll
        for (int r = 0; r < 8; ++r) {
            int i = ib + r;
            eL[r][t] = (i < NENT) ? ldin(E, i*EMB + t, isbf) : 0.f;
        }
        __syncthreads();
        float a8[8];
#pragma unroll
        for (int r = 0; r < 8; ++r) a8[r] = 0.f;
        if (isbf) {
            const __hip_bfloat16* W = (const __hip_bfloat16*)Went;
            for (int k = 0; k < EMB; ++k) {
                float w = __bfloat162float(W[k*EMB + t]);
#pragma unroll
                for (int r = 0; r < 8; ++r) a8[r] += eL[r][k] * w;
            }
        } else {
            const float* W = (const float*)Went;
            for (int k = 0; k < EMB; ++k) {
                float w = W[k*EMB + t];
#pragma unroll
                for (int r = 0; r < 8; ++r) a8[r] += eL[r][k] * w;
            }
        }
#pragma unroll
        for (int r = 0; r < 8; ++r) {
            rows[r][t] = a8[r];
            int i = ib + r;
            if (!part && !ns && i < 200) {   // drug echo, once
                if (isbf) ((__hip_bfloat16*)out)[680000 + i*EMB + t] = __float2bfloat16(a8[r]);
                else      ((float*)out)[680000 + i*EMB + t] = a8[r];
            }
        }
        __syncthreads();

        int n = ns*256 + t;
        float acc[8];
#pragma unroll
        for (int r = 0; r < 8; ++r) acc[r] = 0.f;
        int wbase = part*EMB*KDIM;
        if (isbf) {
            const __hip_bfloat16* W = (const __hip_bfloat16*)W1;
            for (int k = 0; k < EMB; ++k) {
                float w = __bfloat162float(W[wbase + k*KDIM + n]);
#pragma unroll
                for (int r = 0; r < 8; ++r) acc[r] += rows[r][k] * w;
            }
        } else {
            const float* W = (const float*)W1;
            for (int k = 0; k < EMB; ++k) {
                float w = W[wbase + k*KDIM + n];
#pragma unroll
                for (int r = 0; r < 8; ++r) acc[r] += rows[r][k] * w;
            }
        }
        __hip_bfloat16* HX = part ? HB : HA;
        float bv = part ? 0.f : ldin(b1, n, isbf);
#pragma unroll
        for (int r = 0; r < 8; ++r) {
            float v = acc[r];
            if (!part) v += bv;
            HX[(ib + r)*KDIM + n] = __float2bfloat16(v);
        }
    } else {
        // W2H repack for 32x32x16 B frags
        int g = (blockIdx.x - 720)*256 + threadIdx.x;    // 65536
        int lane = g & 63, g32 = (g >> 6) & 7, k16 = (g >> 9) & 63, half = g >> 15;
        int n = half*256 + g32*32 + (lane & 31);
        int kb = k16*16 + (lane >> 5)*8;
        bf16x8 v;
#pragma unroll
        for (int j = 0; j < 8; ++j) {
            v[j] = (__bf16)ldin(W2, (kb + j)*NDIM + n, isbf);
        }
        *(bf16x8*)(W2H + (size_t)g*8) = v;
    }
}

union U8 { bf16x8 v; unsigned u[4]; };

// relu(ha + hb) -> bf16 round-half-up, pair-packed via v_perm
__device__ __forceinline__ bf16x8 mk_af3(bf16x8 ha, bf16x8 hb) {
    U8 r;
#pragma unroll
    for (int j = 0; j < 4; ++j) {
        float x0 = fmaxf((float)ha[2*j]   + (float)hb[2*j],   0.f);
        float x1 = fmaxf((float)ha[2*j+1] + (float)hb[2*j+1], 0.f);
        unsigned u0 = __float_as_uint(x0) + 0x8000u;
        unsigned u1 = __float_as_uint(x1) + 0x8000u;
#if defined(__has_builtin) && __has_builtin(__builtin_amdgcn_perm)
        r.u[j] = __builtin_amdgcn_perm(u1, u0, 0x07060302u);  // {u1.hi16, u0.hi16}
#else
        r.u[j] = (u0 >> 16) | (u1 & 0xFFFF0000u);
#endif
    }
    return r.v;
}

#define MFMA32(a, b, c) __builtin_amdgcn_mfma_f32_32x32x16_bf16((a), (b), (c), 0, 0, 0)

// ---------------- main: fused pair MLP ----------------
// R27: R25 structure (verified local optimum — R17/R20/R21/R24/R26 all lost
// to it) with the MFMA switched 16x16x32 -> 32x32x16:
//  (1) measured pipe rate 2382 vs 2075 TF (+15%, floor 172->150 us);
//  (2) 32 MFMA insts/phase/wave instead of 64 -> issue-slot relief.
// Same tiling/phase order/A-gen cost. A-frag (32m x 16k): lane l holds
// m = l&31 -> i = i0 + mf2*2 + ((l>>4)&1), j_b = l&15; k = (l>>5)*8 + j.
// B regs: 16 frags x 4 VGPR = 64, per-slot rotation. acc[2][4] x f32x16 = 128.
// C/D map (m74/m101-verified): col = lane&31, row = (reg&3)+8*(reg>>2)+4*(lane>>5).
__global__ __launch_bounds__(256, 2) void pair_kernel(
        const ushort_t* __restrict__ HA, const ushort_t* __restrict__ HB,
        const ushort_t* __restrict__ W2H, const void* __restrict__ E,
        const void* __restrict__ b2, const void* __restrict__ W3,
        const void* __restrict__ b3, void* __restrict__ out) {

    const int blkEnd[10] = {650,1300,1800,2300,2800,3450,4100,4594,5088,5582};
    const int aB[10]  = {0,0,0,0,200,200,200,550,400,400};
    const int bB[10]  = {200,0,400,550,400,200,0,0,200,0};
    const int NaT[10] = {200,200,200,200,200,200,200,150,150,150};
    const int NbT[10] = {200,200,150,150,150,200,200,200,200,200};
    const int jTl[10] = {13,13,10,10,10,13,13,13,13,13};
    const int oOf[10] = {0,80000,160000,220000,280000,340000,420000,500000,560000,620000};

    __shared__ __align__(16) unsigned char sAF[16384];  // 2 phases x (4 k16-slots x 2 mf2 x 1 KB)
    __shared__ float lgt[4][64][2];

    int bid = blockIdx.x;
    int ty = 0;
    while (bid >= blkEnd[ty]) ty++;
    int lb = bid - (ty ? blkEnd[ty-1] : 0);
    int jT = jTl[ty];
    int it = lb / jT;
    int jt = lb - it*jT;
    int i0 = aB[ty] + it*4;
    int j0 = bB[ty] + jt*16;

    int tid  = threadIdx.x;
    int lane = tid & 63;
    int w    = tid >> 6;       // 0..3: generates k16-slot w; owns n128-slice w
    int l15  = lane & 15;
    int hi   = lane >> 5;
    int kb16 = ((bid*7) & 31) * 2;   // per-block k-phase stagger (k16 units)

    // B frag byte addr = half*512KB + k16*8KB + g*1KB; wave w: half=w>>1, g = (w&1)*4 + nf
    const char* WB = (const char*)W2H + (size_t)(w >> 1)*524288 + (size_t)((w & 1)*4)*1024 + lane*16;
    const ushort_t* HBq  = HB + (j0 + l15)*KDIM + hi*8;
    const ushort_t* HAq0 = HA + (i0 + ((lane >> 4) & 1))*KDIM + hi*8;
    const ushort_t* HAq1 = HAq0 + 2*KDIM;

    floatx16 acc[2][4];
#pragma unroll
    for (int mf = 0; mf < 2; ++mf)
#pragma unroll
        for (int nf = 0; nf < 4; ++nf)
#pragma unroll
            for (int r = 0; r < 16; ++r) acc[mf][nf][r] = 0.f;

    bf16x8 B4[4][4];   // [k16-slot][nf]
#pragma unroll
    for (int s = 0; s < 4; ++s) {
        int k16 = (kb16 + s) & 63;
#pragma unroll
        for (int nf = 0; nf < 4; ++nf)
            B4[s][nf] = *(const bf16x8*)(WB + (size_t)k16*8192 + nf*1024);
    }

    int kg0 = (kb16 + w) & 63;
    bf16x8 ha0 = *(const bf16x8*)(HAq0 + kg0*16);
    bf16x8 ha1 = *(const bf16x8*)(HAq1 + kg0*16);
    bf16x8 hb  = *(const bf16x8*)(HBq  + kg0*16);

#pragma unroll 1
    for (int ph = 0; ph < 16; ++ph) {
        // A-gen: frags (mf2=0/1, k16-slot w) -> LDS slot w*2KB + mf2*1KB
        char* sW = (char*)sAF + (ph & 1)*8192 + w*2048 + lane*16;
        *(bf16x8*)(sW)        = mk_af3(ha0, hb);
        *(bf16x8*)(sW + 1024) = mk_af3(ha1, hb);
        // next-phase operand prefetch (wraps harmlessly at ph=15)
        int kgn = (kb16 + 4*ph + 4 + w) & 63;
        ha0 = *(const bf16x8*)(HAq0 + kgn*16);
        ha1 = *(const bf16x8*)(HAq1 + kgn*16);
        hb  = *(const bf16x8*)(HBq  + kgn*16);
        LDS_BARRIER();

        const char* sR = (const char*)sAF + (ph & 1)*8192 + lane*16;
#pragma unroll
        for (int s = 0; s < 4; ++s) {
            bf16x8 a0 = *(const bf16x8*)(sR + s*2048);
            bf16x8 a1 = *(const bf16x8*)(sR + s*2048 + 1024);
#pragma unroll
            for (int nf = 0; nf < 4; ++nf)
                acc[0][nf] = MFMA32(a0, B4[s][nf], acc[0][nf]);
#pragma unroll
            for (int nf = 0; nf < 4; ++nf)
                acc[1][nf] = MFMA32(a1, B4[s][nf], acc[1][nf]);
            // refresh this slot's B for next phase
            int k16n = (kb16 + 4*ph + 4 + s) & 63;
#pragma unroll
            for (int nf = 0; nf < 4; ++nf)
                B4[s][nf] = *(const bf16x8*)(WB + (size_t)k16n*8192 + nf*1024);
        }
    }

    // epilogue: h2 = relu(acc + b2); partial logits over this wave's n128; LDS reduce across 4 waves
    int isbf = detect_bf16((const ushort_t*)E);
    float b2v[4], wa[4], wb[4];
#pragma unroll
    for (int nf = 0; nf < 4; ++nf) {
        int n = w*128 + nf*32 + (lane & 31);
        b2v[nf] = ldin(b2, n, isbf);
        wa[nf]  = ldin(W3, 2*n, isbf);
        wb[nf]  = ldin(W3, 2*n+1, isbf);
    }
#pragma unroll
    for (int mf2 = 0; mf2 < 2; ++mf2) {
        float s0[16], s1[16];
#pragma unroll
        for (int r = 0; r < 16; ++r) { s0[r] = 0.f; s1[r] = 0.f; }
#pragma unroll
        for (int nf = 0; nf < 4; ++nf) {
            floatx16 c = acc[mf2][nf];
#pragma unroll
            for (int r = 0; r < 16; ++r) {
                float v = fmaxf(c[r] + b2v[nf], 0.f);
                s0[r] += v * wa[nf];
                s1[r] += v * wb[nf];
            }
        }
#pragma unroll
        for (int off = 1; off < 32; off <<= 1) {
#pragma unroll
            for (int r = 0; r < 16; ++r) {
                s0[r] += __shfl_xor(s0[r], off, 64);
                s1[r] += __shfl_xor(s1[r], off, 64);
            }
        }
        if ((lane & 31) == 0) {
#pragma unroll
            for (int r = 0; r < 16; ++r) {
                int row = mf2*32 + (r & 3) + 8*(r >> 2) + 4*hi;
                lgt[w][row][0] = s0[r];
                lgt[w][row][1] = s1[r];
            }
        }
    }
    __syncthreads();

    if (tid < 64) {
        int p = tid;
        float l0 = lgt[0][p][0] + lgt[1][p][0] + lgt[2][p][0] + lgt[3][p][0];
        float l1 = lgt[0][p][1] + lgt[1][p][1] + lgt[2][p][1] + lgt[3][p][1];
        l0 += ldin(b3, 0, isbf);
        l1 += ldin(b3, 1, isbf);
        int pi = it*4 + (p >> 4), pj = jt*16 + (p & 15);
        if (pi < NaT[ty] && pj < NbT[ty]) {
            float mx = fmaxf(l0, l1);
            float e0 = __expf(l0 - mx), e1 = __expf(l1 - mx);
            float inv = 1.f / (e0 + e1);
            int o = oOf[ty] + (pi*NbT[ty] + pj)*2;
            if (isbf) {
                __hip_bfloat16* ob = (__hip_bfloat16*)out;
                ob[o]   = __float2bfloat16(e0 * inv);
                ob[o+1] = __float2bfloat16(e1 * inv);
            } else {
                float* of = (float*)out;
                of[o]   = e0 * inv;
                of[o+1] = e1 * inv;
            }
        }
    }
}

extern "C" void kernel_launch(void* const* d_in, const int* in_sizes, int n_in,
                              void* d_out, int out_size, void* d_ws, size_t ws_size,
                              hipStream_t stream) {
    const void* E    = d_in[1];
    const void* Went = d_in[3];
    const void* W1   = d_in[5];
    const void* b1   = d_in[6];
    const void* W2   = d_in[7];
    const void* b2   = d_in[8];
    const void* W3   = d_in[9];
    const void* b3   = d_in[10];

    char* ws = (char*)d_ws;
    __hip_bfloat16* HA   = (__hip_bfloat16*)(ws + WS_HA);
    __hip_bfloat16* HB   = (__hip_bfloat16*)(ws + WS_HB);
    __hip_bfloat16* W2H  = (__hip_bfloat16*)(ws + WS_W2H);

    prep_kernel<<<dim3(976), dim3(256), 0, stream>>>(E, Went, W1, b1, W2, W2H, HA, HB, d_out);
    pair_kernel<<<dim3(5582), dim3(256), 0, stream>>>((const ushort_t*)HA, (const ushort_t*)HB,
                                                      (const ushort_t*)W2H, E, b2, W3, b3, d_out);
}

// Round 16
// 450.508 us; speedup vs baseline: 1.1431x; 1.1431x over previous
//
#include <hip/hip_runtime.h>
#include <hip/hip_bf16.h>

typedef __attribute__((ext_vector_type(4))) float floatx4;
typedef __attribute__((ext_vector_type(8))) __bf16 bf16x8;
typedef unsigned short ushort_t;

#define NENT  700
#define EMB   256
#define KDIM  1024
#define NDIM  512
#define HROWS 720   // 90*8: every row written by prep_kernel; reads stay <= 709
#define NPAIR 340000

// ws byte offsets — total ~7.4 MB (WS_ENT retained but unused since R22)
#define WS_HA   0
#define WS_HB   (WS_HA + HROWS*KDIM*2)
#define WS_W2H  (WS_HB + HROWS*KDIM*2)
#define WS_ENT  (WS_W2H + NDIM*KDIM*2)
#define WS_LG   (WS_ENT + NENT*EMB*4)

__device__ __forceinline__ float ldin(const void* p, int i, int isbf) {
    return isbf ? __bfloat162float(((const __hip_bfloat16*)p)[i])
                : ((const float*)p)[i];
}

// per-wave dtype sniff of entity_embedding; deterministic, no cross-kernel dep
__device__ __forceinline__ int detect_bf16(const ushort_t* __restrict__ w) {
    int t = threadIdx.x & 63;
    int e = (w[2*t] >> 7) & 0xFF;
    unsigned long long m = __ballot(e >= 100 && e <= 126);
    return (__popcll(m) >= 48) ? 1 : 0;   // bf16 ~64 hits, f32 ~7
}

// lgkmcnt(0) only; vmcnt untouched -> global prefetches survive the barrier
#define LDS_BARRIER() do { __builtin_amdgcn_s_waitcnt(0xC07F); __builtin_amdgcn_s_barrier(); } while (0)

// ---------------- stage 1 (R24 prep, kept: fine-grained, one launch) ----------------
// R24 verified: non-pair time 124 -> ~57-89 us. 720 heavy blocks (8 rows x
// quarter-N each: ent 2048 + hab 2048 FMA/thread). Accumulation k-ascending
// f32 per output element -> bit-identical (absmax 0.00390625 reproduced).
// blocks 0..719: heavy. b&1=part, (b>>1)&3=nsplit, b>>3=row-tile (8 rows).
// blocks 720..975: W2H repack (unchanged indexing).
__global__ void prep_kernel(const void* __restrict__ E, const void* __restrict__ Went,
                            const void* __restrict__ W1, const void* __restrict__ b1,
                            const void* __restrict__ W2, __hip_bfloat16* __restrict__ W2H,
                            __hip_bfloat16* __restrict__ HA, __hip_bfloat16* __restrict__ HB,
                            void* __restrict__ out) {
    int isbf = detect_bf16((const ushort_t*)E);
    if (blockIdx.x < 720) {
        int part = blockIdx.x & 1;
        int ns   = (blockIdx.x >> 1) & 3;
        int rt   = blockIdx.x >> 3;          // 0..89
        int ib   = rt * 8;
        int t    = threadIdx.x;
        __shared__ float eL[8][EMB];      // E rows (f32)
        __shared__ float rows[8][EMB];    // ent rows (f32)
#pragma unroll
        for (int r = 0; r < 8; ++r) {
            int i = ib + r;
            eL[r][t] = (i < NENT) ? ldin(E, i*EMB + t, isbf) : 0.f;
        }
        __syncthreads();
        // ent rows = eL @ W_ent, column t per thread (same op order as before)
        float a8[8];
#pragma unroll
        for (int r = 0; r < 8; ++r) a8[r] = 0.f;
        if (isbf) {
            const __hip_bfloat16* W = (const __hip_bfloat16*)Went;
            for (int k = 0; k < EMB; ++k) {
                float w = __bfloat162float(W[k*EMB + t]);
#pragma unroll
                for (int r = 0; r < 8; ++r) a8[r] += eL[r][k] * w;
            }
        } else {
            const float* W = (const float*)Went;
            for (int k = 0; k < EMB; ++k) {
                float w = W[k*EMB + t];
#pragma unroll
                for (int r = 0; r < 8; ++r) a8[r] += eL[r][k] * w;
            }
        }
#pragma unroll
        for (int r = 0; r < 8; ++r) {
            rows[r][t] = a8[r];
            int i = ib + r;
            if (!part && !ns && i < 200) {   // drug echo, once
                if (isbf) ((__hip_bfloat16*)out)[680000 + i*EMB + t] = __float2bfloat16(a8[r]);
                else      ((float*)out)[680000 + i*EMB + t] = a8[r];
            }
        }
        __syncthreads();

        // ---- hab: this block's n-quarter (col n per thread), 8 rows ----
        int n = ns*256 + t;
        float acc[8];
#pragma unroll
        for (int r = 0; r < 8; ++r) acc[r] = 0.f;
        int wbase = part*EMB*KDIM;
        if (isbf) {
            const __hip_bfloat16* W = (const __hip_bfloat16*)W1;
            for (int k = 0; k < EMB; ++k) {
                float w = __bfloat162float(W[wbase + k*KDIM + n]);
#pragma unroll
                for (int r = 0; r < 8; ++r) acc[r] += rows[r][k] * w;
            }
        } else {
            const float* W = (const float*)W1;
            for (int k = 0; k < EMB; ++k) {
                float w = W[wbase + k*KDIM + n];
#pragma unroll
                for (int r = 0; r < 8; ++r) acc[r] += rows[r][k] * w;
            }
        }
        __hip_bfloat16* HX = part ? HB : HA;
        float bv = part ? 0.f : ldin(b1, n, isbf);
#pragma unroll
        for (int r = 0; r < 8; ++r) {
            float v = acc[r];
            if (!part) v += bv;
            HX[(ib + r)*KDIM + n] = __float2bfloat16(v);
        }
    } else {
        // W2H: elem ((half*32+kc)*16 + f)*512 + lane*8 + j
        //   = bf16(W2[(kc*32 + (lane>>4)*8 + j)*512 + half*256 + f*16 + (lane&15)])
        int g = (blockIdx.x - 720)*256 + threadIdx.x;    // 65536
        int lane = g & 63, f = (g >> 6) & 15, kc = (g >> 10) & 31, half = g >> 15;
        int l15 = lane & 15, quad = lane >> 4;
        int n = half*256 + f*16 + l15;
        bf16x8 v;
#pragma unroll
        for (int j = 0; j < 8; ++j) {
            int k = kc*32 + quad*8 + j;
            v[j] = (__bf16)ldin(W2, k*NDIM + n, isbf);
        }
        *(bf16x8*)(W2H + (size_t)g*8) = v;
    }
}

union U8 { bf16x8 v; unsigned u[4]; };

// relu(ha + hb) -> bf16 round-half-up, pair-packed via v_perm
__device__ __forceinline__ bf16x8 mk_af3(bf16x8 ha, bf16x8 hb) {
    U8 r;
#pragma unroll
    for (int j = 0; j < 4; ++j) {
        float x0 = fmaxf((float)ha[2*j]   + (float)hb[2*j],   0.f);
        float x1 = fmaxf((float)ha[2*j+1] + (float)hb[2*j+1], 0.f);
        unsigned u0 = __float_as_uint(x0) + 0x8000u;
        unsigned u1 = __float_as_uint(x1) + 0x8000u;
#if defined(__has_builtin) && __has_builtin(__builtin_amdgcn_perm)
        r.u[j] = __builtin_amdgcn_perm(u1, u0, 0x07060302u);  // {u1.hi16, u0.hi16}
#else
        r.u[j] = (u0 >> 16) | (u1 & 0xFFFF0000u);
#endif
    }
    return r.v;
}

#define MFMA(a, b, c) __builtin_amdgcn_mfma_f32_16x16x32_bf16((a), (b), (c), 0, 0, 0)

// ---------------- main: fused pair MLP ----------------
// R28 == R25 byte-for-byte revert (session best: 456 us total, pair 367,
// MfmaUtil 47.8). R27's 32x32x16 MFMA regressed (838 vs 1021 TF achieved:
// narrower acc dependency graph — 8 chains depth-4 vs 32 chains depth-2 —
// starved latency hiding). Six inner-loop deviations have now lost to this
// structure (R17/R20/R21/R24/R26/R27): verified local optimum at ~49% of
// the 16x16 MFMA ubench ceiling. Two independent 4-wave blocks per CU
// (M=64 x N=512, wave owns N=128 = 8 n-frags across both W2 halves).
__global__ __launch_bounds__(256, 2) void pair_kernel(
        const ushort_t* __restrict__ HA, const ushort_t* __restrict__ HB,
        const ushort_t* __restrict__ W2H, const void* __restrict__ E,
        const void* __restrict__ b2, const void* __restrict__ W3,
        const void* __restrict__ b3, void* __restrict__ out) {

    const int blkEnd[10] = {650,1300,1800,2300,2800,3450,4100,4594,5088,5582};
    const int aB[10]  = {0,0,0,0,200,200,200,550,400,400};
    const int bB[10]  = {200,0,400,550,400,200,0,0,200,0};
    const int NaT[10] = {200,200,200,200,200,200,200,150,150,150};
    const int NbT[10] = {200,200,150,150,150,200,200,200,200,200};
    const int jTl[10] = {13,13,10,10,10,13,13,13,13,13};
    const int oOf[10] = {0,80000,160000,220000,280000,340000,420000,500000,560000,620000};

    __shared__ __align__(16) unsigned char sAF[16384];  // 2 phases x (2 kc x 4 m-frags x 1 KB)
    __shared__ float lgt[4][64][2];

    int bid = blockIdx.x;
    int ty = 0;
    while (bid >= blkEnd[ty]) ty++;
    int lb = bid - (ty ? blkEnd[ty-1] : 0);
    int jT = jTl[ty];
    int it = lb / jT;
    int jt = lb - it*jT;
    int i0 = aB[ty] + it*4;
    int j0 = bB[ty] + jt*16;

    int tid  = threadIdx.x;
    int lane = tid & 63;
    int w    = tid >> 6;       // 0..3
    int kcw  = w & 1;          // kc slot this wave generates
    int mp   = (w >> 1) * 2;   // first of its two generated m-frags
    int l15  = lane & 15;
    int quad = lane >> 4;
    int kb   = (bid*7) & 31;   // per-block k-phase stagger

    // B frag byte addr = half*512KB + kc*16KB + f*1KB; wave reads f = w*4+nf of BOTH halves
    const char* WB0 = (const char*)W2H + (size_t)(w*4)*1024 + lane*16;
    const char* WB1 = WB0 + (size_t)512*1024;
    const ushort_t* HBp  = HB + (j0 + l15)*KDIM + quad*8;
    const ushort_t* HAp0 = HA + (i0 + mp)*KDIM + quad*8;
    const ushort_t* HAp1 = HAp0 + KDIM;

    floatx4 acc[4][8];
#pragma unroll
    for (int mf = 0; mf < 4; ++mf)
#pragma unroll
        for (int hf = 0; hf < 8; ++hf) acc[mf][hf] = (floatx4){0.f,0.f,0.f,0.f};

    bf16x8 Bc[2][4], Bn[2][4];
    int k0 = kb, k1 = (kb + 1) & 31;
#pragma unroll
    for (int nf = 0; nf < 4; ++nf) {
        Bc[0][nf] = *(const bf16x8*)(WB0 + (size_t)k0*16384 + nf*1024);
        Bc[1][nf] = *(const bf16x8*)(WB1 + (size_t)k0*16384 + nf*1024);
        Bn[0][nf] = *(const bf16x8*)(WB0 + (size_t)k1*16384 + nf*1024);
        Bn[1][nf] = *(const bf16x8*)(WB1 + (size_t)k1*16384 + nf*1024);
    }
    int kg0 = (kb + kcw) & 31;
    bf16x8 ha0 = *(const bf16x8*)(HAp0 + kg0*32);
    bf16x8 ha1 = *(const bf16x8*)(HAp1 + kg0*32);
    bf16x8 hb  = *(const bf16x8*)(HBp + kg0*32);

#pragma unroll 1
    for (int ph = 0; ph < 16; ++ph) {
        // A-gen: frags (mp,kcw),(mp+1,kcw) -> LDS slot kc*4KB + m*1KB
        char* sW = (char*)sAF + (ph & 1)*8192 + kcw*4096 + mp*1024 + lane*16;
        *(bf16x8*)(sW)        = mk_af3(ha0, hb);
        *(bf16x8*)(sW + 1024) = mk_af3(ha1, hb);
        // next-phase operand prefetch (wraps harmlessly at ph=15)
        int kgn = (kb + 2*ph + 2 + kcw) & 31;
        ha0 = *(const bf16x8*)(HAp0 + kgn*32);
        ha1 = *(const bf16x8*)(HAp1 + kgn*32);
        hb  = *(const bf16x8*)(HBp + kgn*32);
        LDS_BARRIER();

        const char* sR = (const char*)sAF + (ph & 1)*8192 + lane*16;
        int kn2 = (kb + 2*ph + 2) & 31;
        int kn3 = (kb + 2*ph + 3) & 31;
        // sub 0 (kc0): 4 m-frags x 8 (half,nf)
#pragma unroll
        for (int m = 0; m < 4; ++m) {
            bf16x8 a = *(const bf16x8*)(sR + m*1024);
#pragma unroll
            for (int hf = 0; hf < 8; ++hf)
                acc[m][hf] = MFMA(a, Bc[hf>>2][hf&3], acc[m][hf]);
        }
#pragma unroll
        for (int nf = 0; nf < 4; ++nf) {
            Bc[0][nf] = *(const bf16x8*)(WB0 + (size_t)kn2*16384 + nf*1024);
            Bc[1][nf] = *(const bf16x8*)(WB1 + (size_t)kn2*16384 + nf*1024);
        }
        // sub 1 (kc1)
#pragma unroll
        for (int m = 0; m < 4; ++m) {
            bf16x8 a = *(const bf16x8*)(sR + 4096 + m*1024);
#pragma unroll
            for (int hf = 0; hf < 8; ++hf)
                acc[m][hf] = MFMA(a, Bn[hf>>2][hf&3], acc[m][hf]);
        }
#pragma unroll
        for (int nf = 0; nf < 4; ++nf) {
            Bn[0][nf] = *(const bf16x8*)(WB0 + (size_t)kn3*16384 + nf*1024);
            Bn[1][nf] = *(const bf16x8*)(WB1 + (size_t)kn3*16384 + nf*1024);
        }
    }

    // epilogue: h2 = relu(acc + b2); partial logits over this wave's n128; LDS reduce across 4 waves
    int isbf = detect_bf16((const ushort_t*)E);
    float b2v[8], wa[8], wb[8];
#pragma unroll
    for (int hf = 0; hf < 8; ++hf) {
        int n = (hf >> 2)*256 + w*64 + (hf & 3)*16 + l15;
        b2v[hf] = ldin(b2, n, isbf);
        wa[hf]  = ldin(W3, 2*n, isbf);
        wb[hf]  = ldin(W3, 2*n+1, isbf);
    }
#pragma unroll
    for (int mf = 0; mf < 4; ++mf) {
        float s0[4] = {0.f,0.f,0.f,0.f};
        float s1[4] = {0.f,0.f,0.f,0.f};
#pragma unroll
        for (int hf = 0; hf < 8; ++hf) {
            floatx4 c = acc[mf][hf];
#pragma unroll
            for (int r = 0; r < 4; ++r) {
                float v = fmaxf(c[r] + b2v[hf], 0.f);
                s0[r] += v * wa[hf];
                s1[r] += v * wb[hf];
            }
        }
#pragma unroll
        for (int off = 1; off < 16; off <<= 1) {
#pragma unroll
            for (int r = 0; r < 4; ++r) {
                s0[r] += __shfl_xor(s0[r], off, 64);
                s1[r] += __shfl_xor(s1[r], off, 64);
            }
        }
        if (l15 == 0) {
#pragma unroll
            for (int r = 0; r < 4; ++r) {
                int p = mf*16 + quad*4 + r;
                lgt[w][p][0] = s0[r];
                lgt[w][p][1] = s1[r];
            }
        }
    }
    __syncthreads();

    if (tid < 64) {
        int p = tid;
        float l0 = lgt[0][p][0] + lgt[1][p][0] + lgt[2][p][0] + lgt[3][p][0];
        float l1 = lgt[0][p][1] + lgt[1][p][1] + lgt[2][p][1] + lgt[3][p][1];
        l0 += ldin(b3, 0, isbf);
        l1 += ldin(b3, 1, isbf);
        int pi = it*4 + (p >> 4), pj = jt*16 + (p & 15);
        if (pi < NaT[ty] && pj < NbT[ty]) {
            float mx = fmaxf(l0, l1);
            float e0 = __expf(l0 - mx), e1 = __expf(l1 - mx);
            float inv = 1.f / (e0 + e1);
            int o = oOf[ty] + (pi*NbT[ty] + pj)*2;
            if (isbf) {
                __hip_bfloat16* ob = (__hip_bfloat16*)out;
                ob[o]   = __float2bfloat16(e0 * inv);
                ob[o+1] = __float2bfloat16(e1 * inv);
            } else {
                float* of = (float*)out;
                of[o]   = e0 * inv;
                of[o+1] = e1 * inv;
            }
        }
    }
}

extern "C" void kernel_launch(void* const* d_in, const int* in_sizes, int n_in,
                              void* d_out, int out_size, void* d_ws, size_t ws_size,
                              hipStream_t stream) {
    const void* E    = d_in[1];
    const void* Went = d_in[3];
    const void* W1   = d_in[5];
    const void* b1   = d_in[6];
    const void* W2   = d_in[7];
    const void* b2   = d_in[8];
    const void* W3   = d_in[9];
    const void* b3   = d_in[10];

    char* ws = (char*)d_ws;
    __hip_bfloat16* HA   = (__hip_bfloat16*)(ws + WS_HA);
    __hip_bfloat16* HB   = (__hip_bfloat16*)(ws + WS_HB);
    __hip_bfloat16* W2H  = (__hip_bfloat16*)(ws + WS_W2H);

    prep_kernel<<<dim3(976), dim3(256), 0, stream>>>(E, Went, W1, b1, W2, W2H, HA, HB, d_out);
    pair_kernel<<<dim3(5582), dim3(256), 0, stream>>>((const ushort_t*)HA, (const ushort_t*)HB,
                                                      (const ushort_t*)W2H, E, b2, W3, b3, d_out);
}